// Round 1
// baseline (313.177 us; speedup 1.0000x reference)
//
#include <hip/hip_runtime.h>
#include <hip/hip_bf16.h>
#include <stdint.h>

#define B_   4096
#define IN_  1024
#define H_   1024
#define OUT_ 1024

typedef __attribute__((ext_vector_type(8))) short short8;
typedef __attribute__((ext_vector_type(4))) float floatx4;

// ---------- async global->LDS (16B per lane, wave-uniform LDS base) ----------
__device__ static inline void gload_lds16(const void* g, void* l) {
    __builtin_amdgcn_global_load_lds(
        (const __attribute__((address_space(1))) unsigned int*)g,
        (__attribute__((address_space(3))) unsigned int*)l,
        16, 0, 0);
}

__device__ static inline float bfbits2f(unsigned int u) {
    union { unsigned int i; float f; } x; x.i = u << 16; return x.f;
}

// ---------- conversion kernels ----------
// xh[b][c] : c<1024 -> input_vec, else hidden_vec   (bf16, [4096][2048])
__global__ void cvt_xh_kernel(const float* __restrict__ x, const float* __restrict__ h,
                              __hip_bfloat16* __restrict__ out) {
    int idx = blockIdx.x * blockDim.x + threadIdx.x;   // B*512
    int b  = idx >> 9;
    int c4 = (idx & 511) * 4;
    const float* src = (c4 < IN_) ? (x + (size_t)b * IN_ + c4)
                                  : (h + (size_t)b * H_ + (c4 - IN_));
    float4 v = *(const float4*)src;
    __hip_bfloat16* dst = out + (size_t)b * 2048 + c4;
    dst[0] = __float2bfloat16(v.x);
    dst[1] = __float2bfloat16(v.y);
    dst[2] = __float2bfloat16(v.z);
    dst[3] = __float2bfloat16(v.w);
}

struct Ptrs8 { const float* p[8]; };

// Wc[n][k] : n = gate*1024 + r ; k<1024 -> Wx_gate[r][k], else Wh_gate[r][k-1024]
__global__ void cvt_w_kernel(Ptrs8 ptrs, __hip_bfloat16* __restrict__ out) {
    int idx = blockIdx.x * blockDim.x + threadIdx.x;   // 4096*512
    int n  = idx >> 9;
    int c4 = (idx & 511) * 4;
    int gate = n >> 10;
    int r    = n & 1023;
    const float* src = (c4 < 1024) ? (ptrs.p[2 * gate]     + (size_t)r * 1024 + c4)
                                   : (ptrs.p[2 * gate + 1] + (size_t)r * 1024 + (c4 - 1024));
    float4 v = *(const float4*)src;
    __hip_bfloat16* dst = out + (size_t)n * 2048 + c4;
    dst[0] = __float2bfloat16(v.x);
    dst[1] = __float2bfloat16(v.y);
    dst[2] = __float2bfloat16(v.z);
    dst[3] = __float2bfloat16(v.w);
}

__global__ void cvt_kernel(const float* __restrict__ src, __hip_bfloat16* __restrict__ dst, int n4) {
    int idx = blockIdx.x * blockDim.x + threadIdx.x;
    if (idx >= n4) return;
    float4 v = *(const float4*)(src + (size_t)idx * 4);
    __hip_bfloat16* d = dst + (size_t)idx * 4;
    d[0] = __float2bfloat16(v.x);
    d[1] = __float2bfloat16(v.y);
    d[2] = __float2bfloat16(v.z);
    d[3] = __float2bfloat16(v.w);
}

// ---------- bf16 GEMM, C = A * B^T (+bias), m97 structure ----------
// A: [M,K] bf16 row-major, Bm: [N,K] bf16 row-major.
// If Cb != null: write bf16, no bias. Else: write float with bias.
#define BM 128
#define BN 128
#define BK 32

__global__ __launch_bounds__(256) void gemm_bt(
    const __hip_bfloat16* __restrict__ A,
    const __hip_bfloat16* __restrict__ Bm,
    float* __restrict__ C,
    __hip_bfloat16* __restrict__ Cb,
    const float* __restrict__ bias,
    int M, int N, int K)
{
    __shared__ __hip_bfloat16 ldsA[BM * BK];   // 8 KB
    __shared__ __hip_bfloat16 ldsB[BN * BK];   // 8 KB

    const int tid  = threadIdx.x;
    const int lane = tid & 63;
    const int wv   = tid >> 6;       // 0..3
    const int m0   = blockIdx.y * BM;
    const int n0   = blockIdx.x * BN;

    // staging: lane i of wave w covers row w*16 + i/4, 8-elem chunk i%4 (issue0),
    // +64 rows for issue1. LDS layout [row][BK] contiguous == lane-order.
    const int srow = tid >> 2;             // 0..63
    const int scol = (tid & 3) * 8;        // element offset in K-tile
    const __hip_bfloat16* Ag0 = A  + (size_t)(m0 + srow)      * K + scol;
    const __hip_bfloat16* Ag1 = A  + (size_t)(m0 + srow + 64) * K + scol;
    const __hip_bfloat16* Bg0 = Bm + (size_t)(n0 + srow)      * K + scol;
    const __hip_bfloat16* Bg1 = Bm + (size_t)(n0 + srow + 64) * K + scol;
    char* lA0 = (char*)ldsA + wv * 1024;
    char* lA1 = (char*)ldsA + 4096 + wv * 1024;
    char* lB0 = (char*)ldsB + wv * 1024;
    char* lB1 = (char*)ldsB + 4096 + wv * 1024;

    // wave's 64x64 sub-tile
    const int mrow = (wv >> 1) * 64;
    const int ncol = (wv & 1) * 64;
    const int fr   = lane & 15;
    const int koff = (lane >> 4) * 8;

    floatx4 acc[4][4] = {};

    for (int k0 = 0; k0 < K; k0 += BK) {
        gload_lds16(Ag0 + k0, lA0);
        gload_lds16(Ag1 + k0, lA1);
        gload_lds16(Bg0 + k0, lB0);
        gload_lds16(Bg1 + k0, lB1);
        __syncthreads();   // drains vmcnt (global_load_lds) + lgkmcnt

        short8 af[4], bfr[4];
        #pragma unroll
        for (int i = 0; i < 4; ++i)
            af[i] = *(const short8*)((const short*)ldsA + (mrow + i * 16 + fr) * BK + koff);
        #pragma unroll
        for (int j = 0; j < 4; ++j)
            bfr[j] = *(const short8*)((const short*)ldsB + (ncol + j * 16 + fr) * BK + koff);

        #pragma unroll
        for (int i = 0; i < 4; ++i)
            #pragma unroll
            for (int j = 0; j < 4; ++j)
                acc[i][j] = __builtin_amdgcn_mfma_f32_16x16x32_bf16(af[i], bfr[j], acc[i][j], 0, 0, 0);

        __syncthreads();   // protect LDS before next stage
    }

    // epilogue: C/D layout col = lane&15, row = (lane>>4)*4 + reg  [m89/m91]
    const int crow0 = m0 + mrow + (lane >> 4) * 4;
    const int ccol0 = n0 + ncol + (lane & 15);
    #pragma unroll
    for (int i = 0; i < 4; ++i) {
        #pragma unroll
        for (int j = 0; j < 4; ++j) {
            const int col = ccol0 + j * 16;
            #pragma unroll
            for (int r = 0; r < 4; ++r) {
                const int row = crow0 + i * 16 + r;
                const float v = acc[i][j][r];
                if (Cb) {
                    Cb[(size_t)row * N + col] = __float2bfloat16(v);
                } else {
                    C[(size_t)row * N + col] = v + bias[col];
                }
            }
        }
    }
}

// ---------- fused gating ----------
__device__ static inline float sigmoidf_(float x) { return 1.0f / (1.0f + __expf(-x)); }
__device__ static inline float tanhf_(float x)    { return 1.0f - 2.0f / (1.0f + __expf(2.0f * x)); }

__global__ void lstm_gate_kernel(const __hip_bfloat16* __restrict__ gates,  // [B, 4H] bf16
                                 const float* __restrict__ cell,
                                 const float* __restrict__ bxf, const float* __restrict__ bxi,
                                 const float* __restrict__ bxo, const float* __restrict__ bxg,
                                 float* __restrict__ new_hidden, float* __restrict__ new_cell,
                                 __hip_bfloat16* __restrict__ h_bf16) {
    int idx = blockIdx.x * blockDim.x + threadIdx.x;   // B * H/4
    int b  = idx >> 8;
    int h4 = (idx & 255) * 4;
    const __hip_bfloat16* gr = gates + (size_t)b * (4 * H_);

    uint2 qf = *(const uint2*)(gr + h4);
    uint2 qi = *(const uint2*)(gr + H_ + h4);
    uint2 qo = *(const uint2*)(gr + 2 * H_ + h4);
    uint2 qg = *(const uint2*)(gr + 3 * H_ + h4);
    float4 cv = *(const float4*)(cell + (size_t)b * H_ + h4);
    float4 bf = *(const float4*)(bxf + h4);
    float4 bi = *(const float4*)(bxi + h4);
    float4 bo = *(const float4*)(bxo + h4);
    float4 bg = *(const float4*)(bxg + h4);

    float gf[4] = { bfbits2f(qf.x & 0xffffu), bfbits2f(qf.x >> 16), bfbits2f(qf.y & 0xffffu), bfbits2f(qf.y >> 16) };
    float gi[4] = { bfbits2f(qi.x & 0xffffu), bfbits2f(qi.x >> 16), bfbits2f(qi.y & 0xffffu), bfbits2f(qi.y >> 16) };
    float go[4] = { bfbits2f(qo.x & 0xffffu), bfbits2f(qo.x >> 16), bfbits2f(qo.y & 0xffffu), bfbits2f(qo.y >> 16) };
    float gg[4] = { bfbits2f(qg.x & 0xffffu), bfbits2f(qg.x >> 16), bfbits2f(qg.y & 0xffffu), bfbits2f(qg.y >> 16) };
    float cvv[4] = { cv.x, cv.y, cv.z, cv.w };
    float bfv[4] = { bf.x, bf.y, bf.z, bf.w };
    float biv[4] = { bi.x, bi.y, bi.z, bi.w };
    float bov[4] = { bo.x, bo.y, bo.z, bo.w };
    float bgv[4] = { bg.x, bg.y, bg.z, bg.w };

    float nh[4], nc[4];
    #pragma unroll
    for (int r = 0; r < 4; ++r) {
        float f = sigmoidf_(gf[r] + bfv[r]);
        float i = sigmoidf_(gi[r] + biv[r]);
        float o = sigmoidf_(go[r] + bov[r]);
        float g = tanhf_(gg[r] + bgv[r]);
        float c = f * cvv[r] + i * g;
        nc[r] = c;
        nh[r] = o * tanhf_(c);
    }
    size_t base = (size_t)b * H_ + h4;
    *(float4*)(new_hidden + base) = make_float4(nh[0], nh[1], nh[2], nh[3]);
    *(float4*)(new_cell   + base) = make_float4(nc[0], nc[1], nc[2], nc[3]);
    __hip_bfloat16* hb = h_bf16 + base;
    hb[0] = __float2bfloat16(nh[0]);
    hb[1] = __float2bfloat16(nh[1]);
    hb[2] = __float2bfloat16(nh[2]);
    hb[3] = __float2bfloat16(nh[3]);
}

// ---------- launch ----------
extern "C" void kernel_launch(void* const* d_in, const int* in_sizes, int n_in,
                              void* d_out, int out_size, void* d_ws, size_t ws_size,
                              hipStream_t stream) {
    const float* input_vec  = (const float*)d_in[0];
    const float* hidden_vec = (const float*)d_in[1];
    const float* cell_vec   = (const float*)d_in[2];
    const float* Wx_f = (const float*)d_in[3];
    const float* bx_f = (const float*)d_in[4];
    const float* Wh_f = (const float*)d_in[5];
    const float* Wx_i = (const float*)d_in[6];
    const float* bx_i = (const float*)d_in[7];
    const float* Wh_i = (const float*)d_in[8];
    const float* Wx_o = (const float*)d_in[9];
    const float* bx_o = (const float*)d_in[10];
    const float* Wh_o = (const float*)d_in[11];
    const float* Wx_g = (const float*)d_in[12];
    const float* bx_g = (const float*)d_in[13];
    const float* Wh_g = (const float*)d_in[14];
    const float* W_out = (const float*)d_in[15];
    const float* b_out = (const float*)d_in[16];

    char* ws = (char*)d_ws;
    __hip_bfloat16* xh    = (__hip_bfloat16*)(ws);                        // 16 MB [4096][2048]
    __hip_bfloat16* Wc    = (__hip_bfloat16*)(ws + (16ull << 20));        // 16 MB [4096][2048]
    __hip_bfloat16* Wob   = (__hip_bfloat16*)(ws + (32ull << 20));        //  2 MB [1024][1024]
    __hip_bfloat16* gates = (__hip_bfloat16*)(ws + (34ull << 20));        // 32 MB [4096][4096]
    __hip_bfloat16* hb    = (__hip_bfloat16*)(ws + (66ull << 20));        //  8 MB [4096][1024]

    float* new_hidden = (float*)d_out;
    float* new_cell   = new_hidden + (size_t)B_ * H_;
    float* out_vec    = new_cell + (size_t)B_ * H_;

    // conversions
    cvt_xh_kernel<<<(B_ * 512) / 256, 256, 0, stream>>>(input_vec, hidden_vec, xh);
    Ptrs8 p; 
    p.p[0] = Wx_f; p.p[1] = Wh_f; p.p[2] = Wx_i; p.p[3] = Wh_i;
    p.p[4] = Wx_o; p.p[5] = Wh_o; p.p[6] = Wx_g; p.p[7] = Wh_g;
    cvt_w_kernel<<<(4096 * 512) / 256, 256, 0, stream>>>(p, Wc);
    cvt_kernel<<<(1024 * 1024 / 4) / 256, 256, 0, stream>>>(W_out, Wob, 1024 * 1024 / 4);

    // gates = [x|h] @ [Wx|Wh]^T  (bias folded into gating kernel)
    gemm_bt<<<dim3(4 * H_ / BN, B_ / BM), 256, 0, stream>>>(
        xh, Wc, nullptr, gates, nullptr, B_, 4 * H_, 2048);

    // gating + cell/hidden update
    lstm_gate_kernel<<<(B_ * H_ / 4) / 256, 256, 0, stream>>>(
        gates, cell_vec, bx_f, bx_i, bx_o, bx_g, new_hidden, new_cell, hb);

    // output_vec = new_hidden @ W_out^T + b_out
    gemm_bt<<<dim3(OUT_ / BN, B_ / BM), 256, 0, stream>>>(
        hb, Wob, out_vec, nullptr, b_out, B_, OUT_, H_);
}

// Round 2
// 281.454 us; speedup vs baseline: 1.1127x; 1.1127x over previous
//
#include <hip/hip_runtime.h>
#include <hip/hip_bf16.h>
#include <stdint.h>

#define B_   4096
#define IN_  1024
#define H_   1024
#define OUT_ 1024

typedef __attribute__((ext_vector_type(8)))  short short8;
typedef __attribute__((ext_vector_type(16))) float floatx16;

// ---------- async global->LDS (16B per lane; LDS base is wave-uniform, HW adds lane*16) ----------
__device__ static inline void gload_lds16(const void* g, void* l) {
    __builtin_amdgcn_global_load_lds(
        (const __attribute__((address_space(1))) unsigned int*)g,
        (__attribute__((address_space(3))) unsigned int*)l,
        16, 0, 0);
}

__device__ static inline float bfbits2f(unsigned int u) {
    union { unsigned int i; float f; } x; x.i = u << 16; return x.f;
}

// ---------- conversion kernels ----------
__global__ void cvt_xh_kernel(const float* __restrict__ x, const float* __restrict__ h,
                              __hip_bfloat16* __restrict__ out) {
    int idx = blockIdx.x * blockDim.x + threadIdx.x;   // B*512
    int b  = idx >> 9;
    int c4 = (idx & 511) * 4;
    const float* src = (c4 < IN_) ? (x + (size_t)b * IN_ + c4)
                                  : (h + (size_t)b * H_ + (c4 - IN_));
    float4 v = *(const float4*)src;
    __hip_bfloat16* dst = out + (size_t)b * 2048 + c4;
    dst[0] = __float2bfloat16(v.x);
    dst[1] = __float2bfloat16(v.y);
    dst[2] = __float2bfloat16(v.z);
    dst[3] = __float2bfloat16(v.w);
}

struct Ptrs8 { const float* p[8]; };

__global__ void cvt_w_kernel(Ptrs8 ptrs, __hip_bfloat16* __restrict__ out) {
    int idx = blockIdx.x * blockDim.x + threadIdx.x;   // 4096*512
    int n  = idx >> 9;
    int c4 = (idx & 511) * 4;
    int gate = n >> 10;
    int r    = n & 1023;
    const float* src = (c4 < 1024) ? (ptrs.p[2 * gate]     + (size_t)r * 1024 + c4)
                                   : (ptrs.p[2 * gate + 1] + (size_t)r * 1024 + (c4 - 1024));
    float4 v = *(const float4*)src;
    __hip_bfloat16* dst = out + (size_t)n * 2048 + c4;
    dst[0] = __float2bfloat16(v.x);
    dst[1] = __float2bfloat16(v.y);
    dst[2] = __float2bfloat16(v.z);
    dst[3] = __float2bfloat16(v.w);
}

__global__ void cvt_kernel(const float* __restrict__ src, __hip_bfloat16* __restrict__ dst, int n4) {
    int idx = blockIdx.x * blockDim.x + threadIdx.x;
    if (idx >= n4) return;
    float4 v = *(const float4*)(src + (size_t)idx * 4);
    __hip_bfloat16* d = dst + (size_t)idx * 4;
    d[0] = __float2bfloat16(v.x);
    d[1] = __float2bfloat16(v.y);
    d[2] = __float2bfloat16(v.z);
    d[3] = __float2bfloat16(v.w);
}

// ---------- bf16 GEMM, C = A * B^T (+bias), 32x32x16 MFMA, BK=64, XOR-swizzled LDS ----------
// A: [M,K] bf16 row-major, Bm: [N,K] bf16 row-major.
// If Cb != null: write bf16, no bias. Else: write float with bias.
// LDS rows are 64 bf16 = 128 B = 8 chunks of 16 B; chunk c of row r stored at slot c^(r&7)
// -> any 8 consecutive rows cover all 32 banks (b128 read hits the 8-access/bank minimum).
template<int BM, int BN, int WR, int WC>
__global__ __launch_bounds__(256) void gemm_bt(
    const __hip_bfloat16* __restrict__ A,
    const __hip_bfloat16* __restrict__ Bm,
    float* __restrict__ C,
    __hip_bfloat16* __restrict__ Cb,
    const float* __restrict__ bias,
    int M, int N, int K)
{
    constexpr int BK = 64;                 // K-tile elements
    constexpr int TM = BM / WR;            // wave tile rows
    constexpr int TN = BN / WC;            // wave tile cols
    constexpr int AM = TM / 32;            // 32x32 acc tiles per wave (rows)
    constexpr int AN = TN / 32;            // (cols)
    constexpr int AISS = BM * BK * 2 / 4096;   // 4KB global_load_lds issues for A
    constexpr int BISS = BN * BK * 2 / 4096;

    __shared__ __hip_bfloat16 ldsA[BM * BK];
    __shared__ __hip_bfloat16 ldsB[BN * BK];

    const int tid  = threadIdx.x;
    const int lane = tid & 63;
    const int wv   = tid >> 6;
    const int m0   = blockIdx.y * BM;
    const int n0   = blockIdx.x * BN;

    // staging gather: thread tid fills LDS byte slot tid*16 (+ s*4096 per issue)
    //   row = s*32 + tid/8, stored slot = tid%8, so it must fetch global chunk (tid%8)^(row&7)
    const int srow   = tid >> 3;                       // 0..31
    const int schunk = tid & 7;
    const int scg    = schunk ^ (srow & 7);            // global 16B-chunk to fetch
    const __hip_bfloat16* Ag = A  + (size_t)(m0 + srow) * K + scg * 8;
    const __hip_bfloat16* Bg = Bm + (size_t)(n0 + srow) * K + scg * 8;
    char* lA = (char*)ldsA + wv * 1024;                // wave-uniform base, HW adds lane*16
    char* lB = (char*)ldsB + wv * 1024;

    const int wrow  = (wv / WC) * TM;
    const int wcol  = (wv % WC) * TN;
    const int fr    = lane & 31;
    const int khalf = lane >> 5;                       // 0/1 -> k offset 0/8 within 16

    floatx16 acc[AM][AN] = {};

    for (int k0 = 0; k0 < K; k0 += BK) {
        #pragma unroll
        for (int s = 0; s < AISS; ++s)
            gload_lds16(Ag + (size_t)(s * 32) * K + k0, lA + s * 4096);
        #pragma unroll
        for (int s = 0; s < BISS; ++s)
            gload_lds16(Bg + (size_t)(s * 32) * K + k0, lB + s * 4096);
        __syncthreads();   // drains vmcnt (global_load_lds)

        #pragma unroll
        for (int kk = 0; kk < 4; ++kk) {               // k-step of 16
            const int cg = kk * 2 + khalf;             // global chunk of this fragment
            short8 af[AM], bf[AN];
            #pragma unroll
            for (int i = 0; i < AM; ++i) {
                const int r = wrow + i * 32 + fr;
                af[i] = *(const short8*)((const char*)ldsA + r * 128 + (cg ^ (r & 7)) * 16);
            }
            #pragma unroll
            for (int j = 0; j < AN; ++j) {
                const int r = wcol + j * 32 + fr;
                bf[j] = *(const short8*)((const char*)ldsB + r * 128 + (cg ^ (r & 7)) * 16);
            }
            #pragma unroll
            for (int i = 0; i < AM; ++i)
                #pragma unroll
                for (int j = 0; j < AN; ++j)
                    acc[i][j] = __builtin_amdgcn_mfma_f32_32x32x16_bf16(af[i], bf[j], acc[i][j], 0, 0, 0);
        }
        __syncthreads();   // protect LDS before next stage
    }

    // C/D layout (32x32, m74/m101): col = lane&31, row = (reg&3) + 8*(reg>>2) + 4*(lane>>5)
    #pragma unroll
    for (int i = 0; i < AM; ++i) {
        #pragma unroll
        for (int j = 0; j < AN; ++j) {
            const int col = n0 + wcol + j * 32 + fr;
            #pragma unroll
            for (int reg = 0; reg < 16; ++reg) {
                const int row = m0 + wrow + i * 32 + (reg & 3) + 8 * (reg >> 2) + 4 * khalf;
                const float v = acc[i][j][reg];
                if (Cb) {
                    Cb[(size_t)row * N + col] = __float2bfloat16(v);
                } else {
                    C[(size_t)row * N + col] = v + bias[col];
                }
            }
        }
    }
}

// ---------- fused gating ----------
__device__ static inline float sigmoidf_(float x) { return 1.0f / (1.0f + __expf(-x)); }
__device__ static inline float tanhf_(float x)    { return 1.0f - 2.0f / (1.0f + __expf(2.0f * x)); }

__global__ void lstm_gate_kernel(const __hip_bfloat16* __restrict__ gates,  // [B, 4H] bf16
                                 const float* __restrict__ cell,
                                 const float* __restrict__ bxf, const float* __restrict__ bxi,
                                 const float* __restrict__ bxo, const float* __restrict__ bxg,
                                 float* __restrict__ new_hidden, float* __restrict__ new_cell,
                                 __hip_bfloat16* __restrict__ h_bf16) {
    int idx = blockIdx.x * blockDim.x + threadIdx.x;   // B * H/4
    int b  = idx >> 8;
    int h4 = (idx & 255) * 4;
    const __hip_bfloat16* gr = gates + (size_t)b * (4 * H_);

    uint2 qf = *(const uint2*)(gr + h4);
    uint2 qi = *(const uint2*)(gr + H_ + h4);
    uint2 qo = *(const uint2*)(gr + 2 * H_ + h4);
    uint2 qg = *(const uint2*)(gr + 3 * H_ + h4);
    float4 cv = *(const float4*)(cell + (size_t)b * H_ + h4);
    float4 bf = *(const float4*)(bxf + h4);
    float4 bi = *(const float4*)(bxi + h4);
    float4 bo = *(const float4*)(bxo + h4);
    float4 bg = *(const float4*)(bxg + h4);

    float gf[4] = { bfbits2f(qf.x & 0xffffu), bfbits2f(qf.x >> 16), bfbits2f(qf.y & 0xffffu), bfbits2f(qf.y >> 16) };
    float gi[4] = { bfbits2f(qi.x & 0xffffu), bfbits2f(qi.x >> 16), bfbits2f(qi.y & 0xffffu), bfbits2f(qi.y >> 16) };
    float go[4] = { bfbits2f(qo.x & 0xffffu), bfbits2f(qo.x >> 16), bfbits2f(qo.y & 0xffffu), bfbits2f(qo.y >> 16) };
    float gg[4] = { bfbits2f(qg.x & 0xffffu), bfbits2f(qg.x >> 16), bfbits2f(qg.y & 0xffffu), bfbits2f(qg.y >> 16) };
    float cvv[4] = { cv.x, cv.y, cv.z, cv.w };
    float bfv[4] = { bf.x, bf.y, bf.z, bf.w };
    float biv[4] = { bi.x, bi.y, bi.z, bi.w };
    float bov[4] = { bo.x, bo.y, bo.z, bo.w };
    float bgv[4] = { bg.x, bg.y, bg.z, bg.w };

    float nh[4], nc[4];
    #pragma unroll
    for (int r = 0; r < 4; ++r) {
        float f = sigmoidf_(gf[r] + bfv[r]);
        float i = sigmoidf_(gi[r] + biv[r]);
        float o = sigmoidf_(go[r] + bov[r]);
        float g = tanhf_(gg[r] + bgv[r]);
        float c = f * cvv[r] + i * g;
        nc[r] = c;
        nh[r] = o * tanhf_(c);
    }
    size_t base = (size_t)b * H_ + h4;
    *(float4*)(new_hidden + base) = make_float4(nh[0], nh[1], nh[2], nh[3]);
    *(float4*)(new_cell   + base) = make_float4(nc[0], nc[1], nc[2], nc[3]);
    __hip_bfloat16* hb = h_bf16 + base;
    hb[0] = __float2bfloat16(nh[0]);
    hb[1] = __float2bfloat16(nh[1]);
    hb[2] = __float2bfloat16(nh[2]);
    hb[3] = __float2bfloat16(nh[3]);
}

// ---------- launch ----------
extern "C" void kernel_launch(void* const* d_in, const int* in_sizes, int n_in,
                              void* d_out, int out_size, void* d_ws, size_t ws_size,
                              hipStream_t stream) {
    const float* input_vec  = (const float*)d_in[0];
    const float* hidden_vec = (const float*)d_in[1];
    const float* cell_vec   = (const float*)d_in[2];
    const float* Wx_f = (const float*)d_in[3];
    const float* bx_f = (const float*)d_in[4];
    const float* Wh_f = (const float*)d_in[5];
    const float* Wx_i = (const float*)d_in[6];
    const float* bx_i = (const float*)d_in[7];
    const float* Wh_i = (const float*)d_in[8];
    const float* Wx_o = (const float*)d_in[9];
    const float* bx_o = (const float*)d_in[10];
    const float* Wh_o = (const float*)d_in[11];
    const float* Wx_g = (const float*)d_in[12];
    const float* bx_g = (const float*)d_in[13];
    const float* Wh_g = (const float*)d_in[14];
    const float* W_out = (const float*)d_in[15];
    const float* b_out = (const float*)d_in[16];

    char* ws = (char*)d_ws;
    __hip_bfloat16* xh    = (__hip_bfloat16*)(ws);                        // 16 MB [4096][2048]
    __hip_bfloat16* Wc    = (__hip_bfloat16*)(ws + (16ull << 20));        // 16 MB [4096][2048]
    __hip_bfloat16* Wob   = (__hip_bfloat16*)(ws + (32ull << 20));        //  2 MB [1024][1024]
    __hip_bfloat16* gates = (__hip_bfloat16*)(ws + (34ull << 20));        // 32 MB [4096][4096]
    __hip_bfloat16* hb    = (__hip_bfloat16*)(ws + (66ull << 20));        //  8 MB [4096][1024]

    float* new_hidden = (float*)d_out;
    float* new_cell   = new_hidden + (size_t)B_ * H_;
    float* out_vec    = new_cell + (size_t)B_ * H_;

    // conversions
    cvt_xh_kernel<<<(B_ * 512) / 256, 256, 0, stream>>>(input_vec, hidden_vec, xh);
    Ptrs8 p;
    p.p[0] = Wx_f; p.p[1] = Wh_f; p.p[2] = Wx_i; p.p[3] = Wh_i;
    p.p[4] = Wx_o; p.p[5] = Wh_o; p.p[6] = Wx_g; p.p[7] = Wh_g;
    cvt_w_kernel<<<(4096 * 512) / 256, 256, 0, stream>>>(p, Wc);
    cvt_kernel<<<(1024 * 1024 / 4) / 256, 256, 0, stream>>>(W_out, Wob, 1024 * 1024 / 4);

    // gates = [x|h] @ [Wx|Wh]^T  (bias folded into gating kernel)
    gemm_bt<128, 128, 2, 2><<<dim3(4 * H_ / 128, B_ / 128), 256, 0, stream>>>(
        xh, Wc, nullptr, gates, nullptr, B_, 4 * H_, 2048);

    // gating + cell/hidden update
    lstm_gate_kernel<<<(B_ * H_ / 4) / 256, 256, 0, stream>>>(
        gates, cell_vec, bx_f, bx_i, bx_o, bx_g, new_hidden, new_cell, hb);

    // output_vec = new_hidden @ W_out^T + b_out   (128x64 tile -> 512 blocks, 2/CU)
    gemm_bt<128, 64, 4, 1><<<dim3(OUT_ / 64, B_ / 128), 256, 0, stream>>>(
        hb, Wob, out_vec, nullptr, b_out, B_, OUT_, H_);
}

// Round 3
// 248.989 us; speedup vs baseline: 1.2578x; 1.1304x over previous
//
#include <hip/hip_runtime.h>
#include <hip/hip_bf16.h>
#include <stdint.h>

#define B_   4096
#define IN_  1024
#define H_   1024
#define OUT_ 1024

typedef __attribute__((ext_vector_type(8)))  short short8;
typedef __attribute__((ext_vector_type(16))) float floatx16;

// ---------- async global->LDS (16B per lane; LDS base wave-uniform, HW adds lane*16) ----------
__device__ static inline void gload_lds16(const void* g, void* l) {
    __builtin_amdgcn_global_load_lds(
        (const __attribute__((address_space(1))) unsigned int*)g,
        (__attribute__((address_space(3))) unsigned int*)l,
        16, 0, 0);
}

__device__ static inline float sigmoidf_(float x) { return 1.0f / (1.0f + __expf(-x)); }
__device__ static inline float tanhf_(float x)    { return 1.0f - 2.0f / (1.0f + __expf(2.0f * x)); }

// ---------- merged conversion kernel ----------
// blocks [0,8192):    xh[b][c] = bf16(c<1024 ? x[b][c] : h[b][c-1024])        [4096][2048]
// blocks [8192,16384): Wc gate-block interleaved: n = (h>>5)*128 + gate*32 + (h&31)
//                      Wc[n][k] = bf16(k<1024 ? Wx_g[h][k] : Wh_g[h][k-1024]) [4096][2048]
// blocks [16384,17408): Wob = bf16(W_out)                                     [1024][1024]
struct Ptrs8 { const float* p[8]; };

__global__ void cvt_all_kernel(const float* __restrict__ x, const float* __restrict__ h,
                               Ptrs8 ptrs, const float* __restrict__ wout,
                               __hip_bfloat16* __restrict__ xh,
                               __hip_bfloat16* __restrict__ Wc,
                               __hip_bfloat16* __restrict__ Wob) {
    int blk = blockIdx.x;
    const float* src;
    __hip_bfloat16* dst;
    if (blk < 8192) {
        int idx = blk * 256 + threadIdx.x;          // B*512
        int b  = idx >> 9;
        int c4 = (idx & 511) * 4;
        src = (c4 < IN_) ? (x + (size_t)b * IN_ + c4)
                         : (h + (size_t)b * H_ + (c4 - IN_));
        dst = xh + (size_t)b * 2048 + c4;
    } else if (blk < 16384) {
        int idx = (blk - 8192) * 256 + threadIdx.x; // 4096*512
        int n  = idx >> 9;
        int c4 = (idx & 511) * 4;
        int gate = (n >> 5) & 3;
        int hh   = ((n >> 7) << 5) + (n & 31);
        src = (c4 < 1024) ? (ptrs.p[2 * gate]     + (size_t)hh * 1024 + c4)
                          : (ptrs.p[2 * gate + 1] + (size_t)hh * 1024 + (c4 - 1024));
        dst = Wc + (size_t)n * 2048 + c4;
    } else {
        int idx = (blk - 16384) * 256 + threadIdx.x;
        src = wout + (size_t)idx * 4;
        dst = Wob + (size_t)idx * 4;
    }
    float4 v = *(const float4*)src;
    dst[0] = __float2bfloat16(v.x);
    dst[1] = __float2bfloat16(v.y);
    dst[2] = __float2bfloat16(v.z);
    dst[3] = __float2bfloat16(v.w);
}

// ---------- gate GEMM + fused LSTM epilogue ----------
// A = xh [4096][2048] bf16, Bm = Wc [4096][2048] bf16 (gate-block interleaved).
// 128x128 tile, BK=64, 32x32x16 MFMA, WR=4/WC=1 (wave owns 32 rows x all 128 cols
// = 4 gates of the same 32 h). XOR chunk swizzle on LDS (row stride 128B, chunk^(row&7)).
__global__ __launch_bounds__(256) void gemm_gate_fused(
    const __hip_bfloat16* __restrict__ A,
    const __hip_bfloat16* __restrict__ Bm,
    const float* __restrict__ cell,
    const float* __restrict__ bxf, const float* __restrict__ bxi,
    const float* __restrict__ bxo, const float* __restrict__ bxg,
    float* __restrict__ new_hidden, float* __restrict__ new_cell,
    __hip_bfloat16* __restrict__ hb)
{
    constexpr int BK = 64;
    constexpr int K  = 2048;
    constexpr int N  = 4096;

    __shared__ __hip_bfloat16 ldsA[128 * BK];   // 16 KB
    __shared__ __hip_bfloat16 ldsB[128 * BK];   // 16 KB

    const int tid  = threadIdx.x;
    const int lane = tid & 63;
    const int wv   = tid >> 6;

    // XCD swizzle: xcd = bid&7 owns n-tiles [xcd*4, xcd*4+4) (2MB weight stripe -> L2);
    // within XCD, n varies fastest so each A m-tile (512KB) is reused 4x from L2.
    const int bid    = blockIdx.x;             // 1024 blocks
    const int xcd    = bid & 7;
    const int loc    = bid >> 3;               // 0..127
    const int n_tile = xcd * 4 + (loc & 3);
    const int m_tile = loc >> 2;
    const int m0 = m_tile * 128;
    const int n0 = n_tile * 128;

    // staging gather (as R2, verified): thread tid fills LDS slot tid*16 (+s*4096);
    // row = s*32 + tid/8, stored chunk = tid%8 -> fetch global chunk (tid%8)^(row&7)
    const int srow   = tid >> 3;
    const int schunk = tid & 7;
    const int scg    = schunk ^ (srow & 7);
    const __hip_bfloat16* Ag = A  + (size_t)(m0 + srow) * K + scg * 8;
    const __hip_bfloat16* Bg = Bm + (size_t)(n0 + srow) * K + scg * 8;
    char* lA = (char*)ldsA + wv * 1024;
    char* lB = (char*)ldsB + wv * 1024;

    const int wrow  = wv * 32;                 // wave's 32-row band
    const int fr    = lane & 31;
    const int khalf = lane >> 5;

    floatx16 acc[4] = {};                      // j = gate 0..3 (f,i,o,g)

    for (int k0 = 0; k0 < K; k0 += BK) {
        #pragma unroll
        for (int s = 0; s < 4; ++s)
            gload_lds16(Ag + (size_t)(s * 32) * K + k0, lA + s * 4096);
        #pragma unroll
        for (int s = 0; s < 4; ++s)
            gload_lds16(Bg + (size_t)(s * 32) * K + k0, lB + s * 4096);
        __syncthreads();

        #pragma unroll
        for (int kk = 0; kk < 4; ++kk) {
            const int cg = kk * 2 + khalf;
            const int ra = wrow + fr;
            short8 af = *(const short8*)((const char*)ldsA + ra * 128 + ((cg ^ (ra & 7)) * 16));
            short8 bf[4];
            #pragma unroll
            for (int j = 0; j < 4; ++j) {
                const int r = j * 32 + fr;
                bf[j] = *(const short8*)((const char*)ldsB + r * 128 + ((cg ^ (r & 7)) * 16));
            }
            #pragma unroll
            for (int j = 0; j < 4; ++j)
                acc[j] = __builtin_amdgcn_mfma_f32_32x32x16_bf16(af, bf[j], acc[j], 0, 0, 0);
        }
        __syncthreads();
    }

    // fused LSTM epilogue.
    // C/D layout (32x32): col = lane&31, row = (reg&3) + 8*(reg>>2) + 4*(lane>>5).
    // col j*32+fr -> gate j of h = n0/4 + fr. Lane owns all 4 gates of its h.
    const int h  = (n0 >> 2) + fr;
    const float bfb = bxf[h];
    const float bib = bxi[h];
    const float bob = bxo[h];
    const float bgb = bxg[h];
    const int row_base = m0 + wrow + 4 * khalf;

    #pragma unroll
    for (int reg = 0; reg < 16; ++reg) {
        const int row = row_base + (reg & 3) + 8 * (reg >> 2);
        const size_t off = (size_t)row * H_ + h;
        const float f = sigmoidf_(acc[0][reg] + bfb);
        const float i = sigmoidf_(acc[1][reg] + bib);
        const float o = sigmoidf_(acc[2][reg] + bob);
        const float g = tanhf_(acc[3][reg] + bgb);
        const float c = f * cell[off] + i * g;
        const float nh = o * tanhf_(c);
        new_cell[off]   = c;
        new_hidden[off] = nh;
        hb[off] = __float2bfloat16(nh);
    }
}

// ---------- output GEMM: C = A * B^T + bias (fp32 out) ----------
// 128x64 tile, BK=64, WR=4/WC=1. A = hb [4096][1024] bf16, Bm = Wob [1024][1024] bf16.
__global__ __launch_bounds__(256) void gemm_out(
    const __hip_bfloat16* __restrict__ A,
    const __hip_bfloat16* __restrict__ Bm,
    float* __restrict__ C,
    const float* __restrict__ bias)
{
    constexpr int BK = 64;
    constexpr int K  = 1024;
    constexpr int N  = 1024;

    __shared__ __hip_bfloat16 ldsA[128 * BK];  // 16 KB
    __shared__ __hip_bfloat16 ldsB[64 * BK];   //  8 KB

    const int tid  = threadIdx.x;
    const int lane = tid & 63;
    const int wv   = tid >> 6;

    // 512 blocks: xcd owns n-tiles [xcd*2, xcd*2+2)
    const int bid    = blockIdx.x;
    const int xcd    = bid & 7;
    const int loc    = bid >> 3;               // 0..63
    const int n_tile = xcd * 2 + (loc & 1);    // 0..15
    const int m_tile = loc >> 1;               // 0..31
    const int m0 = m_tile * 128;
    const int n0 = n_tile * 64;

    const int srow   = tid >> 3;
    const int schunk = tid & 7;
    const int scg    = schunk ^ (srow & 7);
    const __hip_bfloat16* Ag = A  + (size_t)(m0 + srow) * K + scg * 8;
    const __hip_bfloat16* Bg = Bm + (size_t)(n0 + srow) * K + scg * 8;
    char* lA = (char*)ldsA + wv * 1024;
    char* lB = (char*)ldsB + wv * 1024;

    const int wrow  = wv * 32;
    const int fr    = lane & 31;
    const int khalf = lane >> 5;

    floatx16 acc[2] = {};

    for (int k0 = 0; k0 < K; k0 += BK) {
        #pragma unroll
        for (int s = 0; s < 4; ++s)
            gload_lds16(Ag + (size_t)(s * 32) * K + k0, lA + s * 4096);
        #pragma unroll
        for (int s = 0; s < 2; ++s)
            gload_lds16(Bg + (size_t)(s * 32) * K + k0, lB + s * 4096);
        __syncthreads();

        #pragma unroll
        for (int kk = 0; kk < 4; ++kk) {
            const int cg = kk * 2 + khalf;
            const int ra = wrow + fr;
            short8 af = *(const short8*)((const char*)ldsA + ra * 128 + ((cg ^ (ra & 7)) * 16));
            short8 bf[2];
            #pragma unroll
            for (int j = 0; j < 2; ++j) {
                const int r = j * 32 + fr;
                bf[j] = *(const short8*)((const char*)ldsB + r * 128 + ((cg ^ (r & 7)) * 16));
            }
            #pragma unroll
            for (int j = 0; j < 2; ++j)
                acc[j] = __builtin_amdgcn_mfma_f32_32x32x16_bf16(af, bf[j], acc[j], 0, 0, 0);
        }
        __syncthreads();
    }

    #pragma unroll
    for (int j = 0; j < 2; ++j) {
        const int col = n0 + j * 32 + fr;
        const float bb = bias[col];
        #pragma unroll
        for (int reg = 0; reg < 16; ++reg) {
            const int row = m0 + wrow + 4 * khalf + (reg & 3) + 8 * (reg >> 2);
            C[(size_t)row * N + col] = acc[j][reg] + bb;
        }
    }
}

// ---------- launch ----------
extern "C" void kernel_launch(void* const* d_in, const int* in_sizes, int n_in,
                              void* d_out, int out_size, void* d_ws, size_t ws_size,
                              hipStream_t stream) {
    const float* input_vec  = (const float*)d_in[0];
    const float* hidden_vec = (const float*)d_in[1];
    const float* cell_vec   = (const float*)d_in[2];
    const float* Wx_f = (const float*)d_in[3];
    const float* bx_f = (const float*)d_in[4];
    const float* Wh_f = (const float*)d_in[5];
    const float* Wx_i = (const float*)d_in[6];
    const float* bx_i = (const float*)d_in[7];
    const float* Wh_i = (const float*)d_in[8];
    const float* Wx_o = (const float*)d_in[9];
    const float* bx_o = (const float*)d_in[10];
    const float* Wh_o = (const float*)d_in[11];
    const float* Wx_g = (const float*)d_in[12];
    const float* bx_g = (const float*)d_in[13];
    const float* Wh_g = (const float*)d_in[14];
    const float* W_out = (const float*)d_in[15];
    const float* b_out = (const float*)d_in[16];

    char* ws = (char*)d_ws;
    __hip_bfloat16* xh  = (__hip_bfloat16*)(ws);                        // 16 MB [4096][2048]
    __hip_bfloat16* Wc  = (__hip_bfloat16*)(ws + (16ull << 20));        // 16 MB [4096][2048]
    __hip_bfloat16* Wob = (__hip_bfloat16*)(ws + (32ull << 20));        //  2 MB [1024][1024]
    __hip_bfloat16* hb  = (__hip_bfloat16*)(ws + (34ull << 20));        //  8 MB [4096][1024]

    float* new_hidden = (float*)d_out;
    float* new_cell   = new_hidden + (size_t)B_ * H_;
    float* out_vec    = new_cell + (size_t)B_ * H_;

    Ptrs8 p;
    p.p[0] = Wx_f; p.p[1] = Wh_f; p.p[2] = Wx_i; p.p[3] = Wh_i;
    p.p[4] = Wx_o; p.p[5] = Wh_o; p.p[6] = Wx_g; p.p[7] = Wh_g;
    cvt_all_kernel<<<17408, 256, 0, stream>>>(input_vec, hidden_vec, p, W_out, xh, Wc, Wob);

    // gates GEMM + fused gating: writes new_hidden, new_cell (fp32) and hb (bf16)
    gemm_gate_fused<<<1024, 256, 0, stream>>>(
        xh, Wc, cell_vec, bx_f, bx_i, bx_o, bx_g, new_hidden, new_cell, hb);

    // output_vec = new_hidden @ W_out^T + b_out
    gemm_out<<<512, 256, 0, stream>>>(hb, Wob, out_vec, b_out);
}